// Round 8
// baseline (190.646 us; speedup 1.0000x reference)
//
#include <hip/hip_runtime.h>

#define W      512
#define IMG    (512 * 512)
#define NB     16
#define NPIX   (NB * IMG)
#define BLOCK  256
#define TILE_H 8
#define APRON  3
#define LROWS  (TILE_H + 2 * APRON)   // 14
#define NEDT   1024    // 16 img x 64 tiles of 8 rows
#define NLOSS  256     // 16 img x 8 col-groups(64) x 2 row-halves
#define NTOT   (NEDT + NLOSS)

struct WS {
    unsigned int done;               // memset 0 each launch (4 bytes)
    unsigned int ebmax[NEDT * 4];    // per-EDT-wave max d^2 (plain stores)
    float rows[NB * W];              // w_edt[b, h=b, :]
    float colpart[NLOSS][64];        // per-loss-block column sums of t*d^2
    float lpart[NLOSS][8];           // per-loss-block {pt, pp, st, C, A}
};

// Exactness fallback (P ~ 2^-47 per pixel) — one copy, never inlined.
__device__ __noinline__ int brute_force(const float* __restrict__ img, int h, int y) {
    int nb = 100000000;   // reference BIG when image has no zeros
    for (int gh = 0; gh < W; ++gh) {
        int dhh = gh - h, dh2 = dhh * dhh;
        if (dh2 >= nb) continue;
        const float* rp = img + (gh << 9);
        for (int yy = 0; yy < W; ++yy)
            if (rp[yy] == 0.0f) { int dx = yy - y; nb = min(nb, dh2 + dx * dx); }
    }
    return nb;
}

__global__ __launch_bounds__(BLOCK) void fused_kernel(const float* __restrict__ inp,
                                                      const float* __restrict__ tgt,
                                                      WS* __restrict__ ws,
                                                      float* __restrict__ out) {
    __shared__ unsigned long long zm[LROWS][10];  // bit-mask: cols 1..8 data, 0/9 sentinel
    __shared__ unsigned short Dd[LROWS][W];       // 14 KB row-profile distances
    __shared__ float csm[4][64];
    __shared__ float sredf[4][8];
    __shared__ float fvmax[16], Aimg[16];
    __shared__ double shd[4][6];
    __shared__ int   slast;

    int blk = blockIdx.x, tid = threadIdx.x;
    int wv = tid >> 6, lane = tid & 63;

    if (blk < NEDT) {
        // ================= EDT role (ballot-free LDS bitmask) =================
        int b    = blk >> 6;
        int tile = blk & 63;
        int h0   = tile * TILE_H;
        const float* img = tgt + (size_t)b * IMG;

        // Phase 1: pack 16 px -> u16 zero-mask per unit; 8 independent float4
        // loads per thread, no cross-lane ops, no barrier-forcing waits.
        unsigned short* zms = (unsigned short*)zm;   // u16 view, 4 per u64 word
        #pragma unroll
        for (int pass = 0; pass < 2; ++pass) {
            int u = tid + (pass << 8);               // 0..511, units 448..511 idle
            if (u < LROWS * 32) {
                int lr  = u >> 5;                    // local row
                int sub = u & 31;                    // 16-px unit within row
                int gh  = h0 - APRON + lr;
                unsigned int m = 0;
                if (gh >= 0 && gh < W) {
                    const float4* rp = (const float4*)(img + (gh << 9));
                    #pragma unroll
                    for (int j = 0; j < 4; ++j) {
                        float4 f = rp[(sub << 2) + j];
                        m |= (f.x == 0.0f ? 1u : 0u) << ((j << 2) + 0);
                        m |= (f.y == 0.0f ? 1u : 0u) << ((j << 2) + 1);
                        m |= (f.z == 0.0f ? 1u : 0u) << ((j << 2) + 2);
                        m |= (f.w == 0.0f ? 1u : 0u) << ((j << 2) + 3);
                    }
                }
                // u16 slot: row base 40 u16, data words 1..8, 4 u16/word
                zms[lr * 40 + ((1 + (sub >> 2)) << 2) + (sub & 3)] = (unsigned short)m;
            }
        }
        if (tid < LROWS * 2) zm[tid >> 1][(tid & 1) ? 9 : 0] = 0ULL;  // sentinels
        __syncthreads();

        // Phase 2: 1-D row profiles, branch-free bit windows (verified R3/R4).
        for (int u = wv; u < LROWS * 8; u += 4) {
            int lr = u >> 3, wc = u & 7;
            unsigned long long Wm = zm[lr][wc];
            unsigned long long Wc = zm[lr][wc + 1];
            unsigned long long Wp = zm[lr][wc + 2];
            int off = lane;
            unsigned long long wr = (Wc >> off) | (off ? (Wp << (64 - off)) : 0ULL);
            int dr = wr ? __builtin_ctzll(wr) : 1000;
            unsigned long long vl = off ? ((Wc << (64 - off)) | (Wm >> off)) : Wm;
            int dl = vl ? (1 + __builtin_clzll(vl)) : 1000;
            Dd[lr][(wc << 6) + lane] = (unsigned short)min(min(dr, dl), 1000);
        }
        __syncthreads();

        // Phase 3: 7-term combine; exact iff best <= 16 (|dh|>=4 => d^2>=16).
        unsigned int bmax = 0;
        #pragma unroll
        for (int k = 0; k < TILE_H * W / BLOCK; ++k) {   // 16 px/thread
            int p  = tid + (k << 8);
            int y  = p & (W - 1);
            int hl = p >> 9;
            int lr = hl + APRON;
            int d0 = Dd[lr][y];
            int a1 = Dd[lr - 1][y], b1 = Dd[lr + 1][y];
            int a2 = Dd[lr - 2][y], b2 = Dd[lr + 2][y];
            int a3 = Dd[lr - 3][y], b3 = Dd[lr + 3][y];
            int m1 = min(a1, b1), m2 = min(a2, b2), m3 = min(a3, b3);
            int best = min(min(d0 * d0, 1 + m1 * m1),
                           min(4 + m2 * m2, 9 + m3 * m3));
            if (best > 16) best = brute_force(img, h0 + hl, y);
            if (h0 + hl == b) ws->rows[(b << 9) + y] = sqrtf((float)best);
            bmax = max(bmax, (unsigned int)best);
        }
        #pragma unroll
        for (int o = 32; o > 0; o >>= 1)
            bmax = max(bmax, (unsigned int)__shfl_down((int)bmax, o));
        if (lane == 0) ws->ebmax[(blk << 2) + wv] = bmax;
    } else {
        // ================= loss role (atomic-free, verified R5) =================
        int lid  = blk - NEDT;           // 0..255
        int b    = lid >> 4;
        int cg   = (lid >> 1) & 7;
        int half = lid & 1;
        int c    = (cg << 6) + lane;
        const float* ip = inp + (size_t)b * IMG;
        const float* tp = tgt + (size_t)b * IMG;
        float cs = 0.f, pt = 0.f, pp = 0.f, st = 0.f, Cc = 0.f, Aa = 0.f;
        int rbase = (half << 8) + wv;
        #pragma unroll 8
        for (int k = 0; k < 64; ++k) {
            int off = ((rbase + (k << 2)) << 9) + c;
            float x = ip[off], t = tp[off];
            float d = x - t, dd = d * d;
            Cc += dd;
            float td2 = t * dd; Aa += td2; cs += td2;
            float p = 1.0f / (1.0f + __expf(-x));
            pt += p * t; pp += p; st += t;
        }
        csm[wv][lane] = cs;
        #pragma unroll
        for (int o = 32; o > 0; o >>= 1) {
            pt += __shfl_down(pt, o); pp += __shfl_down(pp, o);
            st += __shfl_down(st, o); Cc += __shfl_down(Cc, o);
            Aa += __shfl_down(Aa, o);
        }
        if (lane == 0) { sredf[wv][0] = pt; sredf[wv][1] = pp; sredf[wv][2] = st;
                         sredf[wv][3] = Cc; sredf[wv][4] = Aa; }
        __syncthreads();
        if (tid < 64)
            ws->colpart[lid][tid] = csm[0][tid] + csm[1][tid] + csm[2][tid] + csm[3][tid];
        if (tid == 0) {
            float a0 = 0, a1 = 0, a2 = 0, a3 = 0, a4 = 0;
            #pragma unroll
            for (int i = 0; i < 4; ++i) {
                a0 += sredf[i][0]; a1 += sredf[i][1]; a2 += sredf[i][2];
                a3 += sredf[i][3]; a4 += sredf[i][4];
            }
            float* pr = ws->lpart[lid];
            pr[0] = a0; pr[1] = a1; pr[2] = a2; pr[3] = a3; pr[4] = a4;
        }
    }

    // ============ last-block finalize (device-scope handshake) ============
    __threadfence();
    __syncthreads();
    if (tid == 0)
        slast = (atomicAdd(&ws->done, 1u) == (unsigned int)(NTOT - 1));
    __syncthreads();
    if (!slast) return;
    __threadfence();   // acquire

    // per-image vmax (16 threads/image over 256 ebmax slots) and A_b
    int bimg = tid >> 4, j = tid & 15;
    unsigned int mx = 0;
    #pragma unroll
    for (int k = 0; k < 16; ++k)
        mx = max(mx, ws->ebmax[(bimg << 8) + (j << 4) + k]);
    float a4 = ws->lpart[(bimg << 4) + j][4];
    #pragma unroll
    for (int o = 8; o > 0; o >>= 1) {
        mx = max(mx, (unsigned int)__shfl_down((int)mx, o));
        a4 += __shfl_down(a4, o);
    }
    if (j == 0) { fvmax[bimg] = sqrtf((float)mx); Aimg[bimg] = a4; }

    const float* pr = ws->lpart[tid];    // NLOSS == BLOCK
    double pt = pr[0], pp = pr[1], st = pr[2], C = pr[3];
    __syncthreads();

    double dot = 0.0;
    for (int i = tid; i < NB * W; i += BLOCK) {
        int bb = i >> 9, y = i & 511;
        int lidb = (bb << 4) + (((y >> 6) & 7) << 1);
        float scol = ws->colpart[lidb][y & 63] + ws->colpart[lidb + 1][y & 63];
        dot += (double)ws->rows[i] * (double)scol;
    }
    double vA = (tid < 16) ? (double)fvmax[tid] * (double)Aimg[tid] : 0.0;

    #pragma unroll
    for (int o = 32; o > 0; o >>= 1) {
        pt += __shfl_down(pt, o); pp += __shfl_down(pp, o);
        st += __shfl_down(st, o); C  += __shfl_down(C, o);
        dot += __shfl_down(dot, o); vA += __shfl_down(vA, o);
    }
    if (lane == 0) { shd[wv][0] = pt; shd[wv][1] = pp; shd[wv][2] = st;
                     shd[wv][3] = C;  shd[wv][4] = dot; shd[wv][5] = vA; }
    __syncthreads();
    if (tid == 0) {
        double a0 = 0, a1 = 0, a2 = 0, a3 = 0, a5 = 0, a6 = 0;
        #pragma unroll
        for (int i = 0; i < 4; ++i) {
            a0 += shd[i][0]; a1 += shd[i][1]; a2 += shd[i][2];
            a3 += shd[i][3]; a5 += shd[i][4]; a6 += shd[i][5];
        }
        double wsum = a6 - a5 + 0.001 * a3;   // v·A - rows·Scol + eps·C
        out[0] = (float)(0.6 * (wsum / (double)NPIX));
        out[1] = (float)(1.0 - (2.0 * a0 + 1e-6) / (a1 + a2 + 1e-6));
    }
}

extern "C" void kernel_launch(void* const* d_in, const int* in_sizes, int n_in,
                              void* d_out, int out_size, void* d_ws, size_t ws_size,
                              hipStream_t stream) {
    const float* inp = (const float*)d_in[0];
    const float* tgt = (const float*)d_in[1];
    float* out = (float*)d_out;
    WS* ws = (WS*)d_ws;

    hipMemsetAsync(&ws->done, 0, sizeof(unsigned int), stream);
    fused_kernel<<<NTOT, BLOCK, 0, stream>>>(inp, tgt, ws, out);
}